// Round 1
// baseline (117.268 us; speedup 1.0000x reference)
//
#include <hip/hip_runtime.h>
#include <math.h>

#define POOL 7
#define FH 50
#define FW 50
#define FC 1024
#define FC4 (FC / 4)        // 256 float4 groups per spatial cell
#define CHUNKS 4            // channel chunks; 64 float4 (256 ch) per chunk
#define F4C 64              // float4 per cell per chunk (one wave-wide load)
#define ROWSTRIDE (FW * FC4)

typedef float vf4 __attribute__((ext_vector_type(4)));

static __device__ __forceinline__ vf4 vmax4(vf4 a, vf4 b) {
    vf4 r;
    r.x = fmaxf(a.x, b.x);
    r.y = fmaxf(a.y, b.y);
    r.z = fmaxf(a.z, b.z);
    r.w = fmaxf(a.w, b.w);
    return r;
}

// XCD-partitioned RoI max-pool, row-bin-per-wave decomposition.
//
// Work unit: wave = (roi n, row-bin i, channel chunk). Each wave computes all
// 7 column bins of its row-bin with 7 live vf4 accumulators, traversing its
// row range once. vs the previous bin-per-wave version this is 7x fewer waves
// (58800 -> 8400), 7x less per-wave setup (ROI load, int divisions, bounds),
// and ~19 independent loads per row feeding 7 independent acc chains (MLP)
// instead of ~2 loads chained on one accumulator.
//
// Workgroup->XCD is round-robin by linear block id (b % 8), so chunk = b & 3
// pins each XCD to ONE channel chunk: its 2.56 MB fm slice stays L2-resident
// (4 MB/XCD) and serves the ~42x cross-ROI reuse at L2 bandwidth.
__global__ __launch_bounds__(256) void roipool_kernel(
    const float* __restrict__ fm,     // [FH, FW, FC]
    const float* __restrict__ rois,   // [N, 4] (y1, x1, y2, x2) normalized
    float* __restrict__ out,          // [N, 7, 7, FC]
    int nunits)                       // N * POOL row-bin units
{
    const int b     = blockIdx.x;
    const int chunk = b & (CHUNKS - 1);       // pinned per XCD (b%8 round-robin)
    const int wave  = threadIdx.x >> 6;
    const int lane  = threadIdx.x & 63;
    const int unit  = (b >> 2) * 4 + wave;    // n*7 + i
    if (unit >= nunits) return;

    const int n = unit / POOL;
    const int i = unit - n * POOL;

    // ROI corners: truncating float->int cast, matching jnp astype(int32)
    const float4 roi = reinterpret_cast<const float4*>(rois)[n];
    const int h0 = (int)((float)FH * roi.x);
    const int w0 = (int)((float)FW * roi.y);
    const int h1 = (int)((float)FH * roi.z);
    const int w1 = (int)((float)FW * roi.w);
    const int rh = h1 - h0;
    const int rw = w1 - w0;
    const int hstep = rh / POOL;
    const int wstep = rw / POOL;

    // row-bin bounds (region-relative) + empty-bin adjustment
    int sh = i * hstep;
    int eh = (i < POOL - 1) ? (i + 1) * hstep : rh;
    if (sh == eh) { if (eh < rh) eh += 1; else sh -= 1; }
    const int r0 = max(0, h0 + sh);
    const int r1 = min(FH, h0 + eh);

    // all 7 column-bin bounds (global, clamped). Arrays are only ever indexed
    // with compile-time-constant j (unrolled loops) -> stay in registers.
    int c0[POOL], c1[POOL];
#pragma unroll
    for (int j = 0; j < POOL; ++j) {
        int sw = j * wstep;
        int ew = (j < POOL - 1) ? (j + 1) * wstep : rw;
        if (sw == ew) { if (ew < rw) ew += 1; else sw -= 1; }
        c0[j] = max(0, w0 + sw);
        c1[j] = min(FW, w0 + ew);
    }

    // this wave's float4 index within a cell for its pinned channel chunk
    const int f4 = chunk * F4C + lane;        // [0, 256)
    const vf4* fmbase = reinterpret_cast<const vf4*>(fm) + f4;

    vf4 acc[POOL];
#pragma unroll
    for (int j = 0; j < POOL; ++j) {
        acc[j].x = -INFINITY; acc[j].y = -INFINITY;
        acc[j].z = -INFINITY; acc[j].w = -INFINITY;
    }

    for (int r = r0; r < r1; ++r) {
        const vf4* rowp = fmbase + r * ROWSTRIDE;
#pragma unroll
        for (int j = 0; j < POOL; ++j) {
            int c = c0[j];
            const int ce = c1[j];
            for (; c + 1 < ce; c += 2) {
                vf4 a  = rowp[c * FC4];
                vf4 b2 = rowp[(c + 1) * FC4];
                acc[j] = vmax4(acc[j], vmax4(a, b2));
            }
            if (c < ce) {
                acc[j] = vmax4(acc[j], rowp[c * FC4]);
            }
        }
    }

    // 7 output cells: gid = n*49 + i*7 + j, stride FC4 float4 between cells
    vf4* o = reinterpret_cast<vf4*>(out) + (size_t)(n * 49 + i * 7) * FC4 + f4;
#pragma unroll
    for (int j = 0; j < POOL; ++j) {
        __builtin_nontemporal_store(acc[j], o + (size_t)j * FC4);
    }
}

extern "C" void kernel_launch(void* const* d_in, const int* in_sizes, int n_in,
                              void* d_out, int out_size, void* d_ws, size_t ws_size,
                              hipStream_t stream) {
    const float* features = (const float*)d_in[0];  // [1,50,50,1024]
    const float* rois     = (const float*)d_in[1];  // [N,4]
    float* out            = (float*)d_out;          // [N,7,7,1024]
    const int N = in_sizes[1] / 4;

    const int nunits = N * POOL;                    // 2100 row-bin units
    // linear grid: block b -> chunk b&3 (XCD-pinned), units (b>>2)*4 + wave
    dim3 grid(((nunits + 3) / 4) * CHUNKS);
    dim3 block(256);
    roipool_kernel<<<grid, block, 0, stream>>>(features, rois, out, nunits);
}

// Round 2
// 98.596 us; speedup vs baseline: 1.1894x; 1.1894x over previous
//
#include <hip/hip_runtime.h>
#include <math.h>

#define POOL 7
#define FH 50
#define FW 50
#define FC 1024
#define FC4 (FC / 4)        // 256 float4 groups per spatial cell
#define CHUNKS 4            // channel chunks; 64 float4 (256 ch) per chunk
#define F4C 64              // float4 per cell per chunk (one wave-wide load)
#define ROWSTRIDE (FW * FC4)
#define JGROUPS 4           // column-bin groups: {0,1},{2,3},{4,5},{6}
#define UNITS_PER_ROI (POOL * JGROUPS)   // 28

typedef float vf4 __attribute__((ext_vector_type(4)));

static __device__ __forceinline__ vf4 vmax4(vf4 a, vf4 b) {
    vf4 r;
    r.x = fmaxf(a.x, b.x);
    r.y = fmaxf(a.y, b.y);
    r.z = fmaxf(a.z, b.z);
    r.w = fmaxf(a.w, b.w);
    return r;
}

// XCD-partitioned RoI max-pool, (row-bin x col-bin-pair)-per-wave.
//
// Round-1 lesson: the row-bin-per-wave version (8400 waves, 2100 blocks) had
// no backfill (8.2 blocks/CU = one residency generation) and a straggler
// tail -> OccupancyPercent 15.8%, 64 us. The op is latency-bound (L2-read
// floor ~12 us needs ~17 1KB-loads in flight per CU), so concurrency wins.
//
// This version: wave = (roi n, row-bin i, col-bin pair jg, chunk).
// 33,600 waves / 8,400 blocks = ~33 blocks/CU nominal = ~4 backfill
// generations (tail resilience of the original bin-per-wave kernel), while
// still amortizing ROI setup over 2 bins and running 2 independent acc
// chains per wave (~4-8 loads in flight per row).
//
// Workgroup->XCD is round-robin by linear block id (b % 8), so chunk = b & 3
// pins each XCD to ONE channel chunk: its 2.56 MB fm slice stays L2-resident
// (4 MB/XCD). Round-1 FETCH_SIZE = 8.3 MB ~= fm read from HBM once confirms
// this works; preserved unchanged.
__global__ __launch_bounds__(256) void roipool_kernel(
    const float* __restrict__ fm,     // [FH, FW, FC]
    const float* __restrict__ rois,   // [N, 4] (y1, x1, y2, x2) normalized
    float* __restrict__ out,          // [N, 7, 7, FC]
    int nunits)                       // N * POOL * JGROUPS units
{
    const int b     = blockIdx.x;
    const int chunk = b & (CHUNKS - 1);       // pinned per XCD (b%8 round-robin)
    const int wave  = threadIdx.x >> 6;
    const int lane  = threadIdx.x & 63;
    const int u     = (b >> 2) * 4 + wave;    // ((n*7 + i)*4 + jg)
    if (u >= nunits) return;

    const int n   = u / UNITS_PER_ROI;
    const int rem = u - n * UNITS_PER_ROI;
    const int i   = rem >> 2;
    const int jg  = rem & 3;
    const int j0  = jg * 2;                   // first col bin of this group
    const int jcnt = (jg < JGROUPS - 1) ? 2 : 1;

    // ROI corners: truncating float->int cast, matching jnp astype(int32)
    const float4 roi = reinterpret_cast<const float4*>(rois)[n];
    const int h0 = (int)((float)FH * roi.x);
    const int w0 = (int)((float)FW * roi.y);
    const int h1 = (int)((float)FH * roi.z);
    const int w1 = (int)((float)FW * roi.w);
    const int rh = h1 - h0;
    const int rw = w1 - w0;
    const int hstep = rh / POOL;
    const int wstep = rw / POOL;

    // row-bin bounds (region-relative) + empty-bin adjustment
    int sh = i * hstep;
    int eh = (i < POOL - 1) ? (i + 1) * hstep : rh;
    if (sh == eh) { if (eh < rh) eh += 1; else sh -= 1; }
    const int r0 = max(0, h0 + sh);
    const int r1 = min(FH, h0 + eh);

    // col bounds for this wave's (up to) 2 bins; indexed only by
    // compile-time-constant t (unrolled) -> registers.
    int c0[2], c1[2];
#pragma unroll
    for (int t = 0; t < 2; ++t) {
        const int j = j0 + t;
        if (j < POOL) {
            int sw = j * wstep;
            int ew = (j < POOL - 1) ? (j + 1) * wstep : rw;
            if (sw == ew) { if (ew < rw) ew += 1; else sw -= 1; }
            c0[t] = max(0, w0 + sw);
            c1[t] = min(FW, w0 + ew);
        } else {
            c0[t] = 0; c1[t] = 0;            // empty range, acc unused
        }
    }

    // this wave's float4 index within a cell for its pinned channel chunk
    const int f4 = chunk * F4C + lane;        // [0, 256)
    const vf4* fmbase = reinterpret_cast<const vf4*>(fm) + f4;

    vf4 acc[2];
#pragma unroll
    for (int t = 0; t < 2; ++t) {
        acc[t].x = -INFINITY; acc[t].y = -INFINITY;
        acc[t].z = -INFINITY; acc[t].w = -INFINITY;
    }

    for (int r = r0; r < r1; ++r) {
        const vf4* rowp = fmbase + r * ROWSTRIDE;
#pragma unroll
        for (int t = 0; t < 2; ++t) {
            int c = c0[t];
            const int ce = c1[t];
            for (; c + 1 < ce; c += 2) {
                vf4 a  = rowp[c * FC4];
                vf4 b2 = rowp[(c + 1) * FC4];
                acc[t] = vmax4(acc[t], vmax4(a, b2));
            }
            if (c < ce) {
                acc[t] = vmax4(acc[t], rowp[c * FC4]);
            }
        }
    }

    // output cells: gid = n*49 + i*7 + (j0 + t)
    vf4* o = reinterpret_cast<vf4*>(out) + (size_t)(n * 49 + i * 7 + j0) * FC4 + f4;
    __builtin_nontemporal_store(acc[0], o);
    if (jcnt == 2) {
        __builtin_nontemporal_store(acc[1], o + (size_t)FC4);
    }
}

extern "C" void kernel_launch(void* const* d_in, const int* in_sizes, int n_in,
                              void* d_out, int out_size, void* d_ws, size_t ws_size,
                              hipStream_t stream) {
    const float* features = (const float*)d_in[0];  // [1,50,50,1024]
    const float* rois     = (const float*)d_in[1];  // [N,4]
    float* out            = (float*)d_out;          // [N,7,7,1024]
    const int N = in_sizes[1] / 4;

    const int nunits = N * UNITS_PER_ROI;           // 8400 units
    // linear grid: block b -> chunk b&3 (XCD-pinned), units (b>>2)*4 + wave
    dim3 grid(((nunits + 3) / 4) * CHUNKS);         // 8400 blocks
    dim3 block(256);
    roipool_kernel<<<grid, block, 0, stream>>>(features, rois, out, nunits);
}